// Round 4
// baseline (247.000 us; speedup 1.0000x reference)
//
#include <hip/hip_runtime.h>

// z = segment_sum( (x @ W_fc^T)[col], row )  -- alpha==1 (softmax over singleton dim)
//
// Round 4: replace the 51.2M-float-atomic scatter (204.8 MB HBM write-through,
// 172 us) with counting-sort CSR + atomic-free per-node gather.

// ---------- Kernel 1: y = x @ Wfc^T (unchanged this round) ----------
__global__ void fc_kernel(const float* __restrict__ x, const float* __restrict__ Wfc,
                          float* __restrict__ y, int N) {
    __shared__ float sW[64][65];
    __shared__ float sX[4][64];
    for (int i = threadIdx.x; i < 64 * 64; i += 256) sW[i >> 6][i & 63] = Wfc[i];
    int r   = threadIdx.x >> 6;
    int co  = threadIdx.x & 63;
    int gRow = (blockIdx.x << 2) + r;
    sX[r][co] = (gRow < N) ? x[gRow * 64 + co] : 0.f;
    __syncthreads();
    if (gRow >= N) return;
    float acc = 0.f;
#pragma unroll
    for (int k = 0; k < 64; ++k) acc = fmaf(sX[r][k], sW[co][k], acc);
    y[gRow * 64 + co] = acc;
}

// ---------- Kernel 2: degree histogram (counts at index r+1) ----------
__global__ void hist_kernel(const int* __restrict__ eidx, int* __restrict__ cnt, int E) {
    int i = blockIdx.x * blockDim.x + threadIdx.x;
    int n = gridDim.x * blockDim.x;
    for (int e = i; e < E; e += n) atomicAdd(&cnt[eidx[e] + 1], 1);
}

// ---------- Kernel 3: single-block inclusive prefix scan over n entries ----------
__global__ void scan_kernel(int* __restrict__ a, int n) {
    __shared__ int sums[1024];
    int t = threadIdx.x;
    int chunk = (n + 1023) >> 10;
    int lo = t * chunk;
    int hi = lo + chunk; if (hi > n) hi = n;
    int s = 0;
    for (int i = lo; i < hi; ++i) s += a[i];
    sums[t] = s;
    __syncthreads();
    for (int off = 1; off < 1024; off <<= 1) {
        int v = sums[t];
        int u = (t >= off) ? sums[t - off] : 0;
        __syncthreads();
        sums[t] = v + u;
        __syncthreads();
    }
    int run = (t > 0) ? sums[t - 1] : 0;
    for (int i = lo; i < hi; ++i) { run += a[i]; a[i] = run; }
}

// ---------- Kernel 4: scatter col values into CSR order ----------
__global__ void fill_kernel(const int* __restrict__ eidx, int* __restrict__ cursor,
                            int* __restrict__ scol, int E) {
    int i = blockIdx.x * blockDim.x + threadIdx.x;
    int n = gridDim.x * blockDim.x;
    for (int e = i; e < E; e += n) {
        int r = eidx[e];
        int c = eidx[E + e];
        int p = atomicAdd(&cursor[r], 1);
        scol[p] = c;
    }
}

// ---------- Kernel 5: atomic-free gather — one wave (64 lanes = channels) per node ----------
__global__ void gather_kernel(const int* __restrict__ start, const int* __restrict__ scol,
                              const float* __restrict__ y, float* __restrict__ z, int N) {
    int lane = threadIdx.x & 63;
    int g    = (int)((blockIdx.x * blockDim.x + threadIdx.x) >> 6);
    int nG   = (int)((gridDim.x * blockDim.x) >> 6);
    for (int node = g; node < N; node += nG) {
        int e0 = start[node], e1 = start[node + 1];
        float acc0 = 0.f, acc1 = 0.f;
        int j = e0;
        for (; j + 1 < e1; j += 2) {              // 2-deep ILP on the dependent load chain
            int c0 = scol[j], c1 = scol[j + 1];   // wave-uniform loads
            acc0 += y[(size_t)c0 * 64 + lane];    // coalesced 256B/wave
            acc1 += y[(size_t)c1 * 64 + lane];
        }
        if (j < e1) acc0 += y[(size_t)scol[j] * 64 + lane];
        z[(size_t)node * 64 + lane] = acc0 + acc1;  // single non-atomic write
    }
}

// ---------- fallback (ws too small): original atomic scatter ----------
__global__ void scatter_kernel(const int* __restrict__ eidx, const float* __restrict__ y,
                               float* __restrict__ z, int E) {
    int lane  = threadIdx.x & 63;
    int group = (int)((blockIdx.x * blockDim.x + threadIdx.x) >> 6);
    int nG    = (int)((gridDim.x * blockDim.x) >> 6);
    for (int e = group; e < E; e += nG) {
        int r = eidx[e];
        int c = eidx[E + e];
        atomicAdd(&z[r * 64 + lane], y[c * 64 + lane]);
    }
}

extern "C" void kernel_launch(void* const* d_in, const int* in_sizes, int n_in,
                              void* d_out, int out_size, void* d_ws, size_t ws_size,
                              hipStream_t stream) {
    const float* x    = (const float*)d_in[0];
    const int*   eidx = (const int*)d_in[1];
    const float* Wfc  = (const float*)d_in[3];   // d_in[2,4,5] unused (alpha==1)
    float*       z    = (float*)d_out;

    int N = in_sizes[0] / 64;
    int E = in_sizes[1] / 2;

    // workspace layout
    char* w = (char*)d_ws;
    size_t off = 0;
    float* y = (float*)(w + off);  off += (size_t)N * 64 * sizeof(float);
    off = (off + 255) & ~(size_t)255;
    int* start = (int*)(w + off);  off += (size_t)(N + 1) * sizeof(int);
    off = (off + 255) & ~(size_t)255;
    int* cursor = (int*)(w + off); off += (size_t)N * sizeof(int);
    off = (off + 255) & ~(size_t)255;
    int* scol = (int*)(w + off);   off += (size_t)E * sizeof(int);

    fc_kernel<<<(N + 3) / 4, 256, 0, stream>>>(x, Wfc, y, N);

    if (ws_size >= off) {
        hipMemsetAsync(start, 0, (size_t)(N + 1) * sizeof(int), stream);
        hist_kernel<<<1024, 256, 0, stream>>>(eidx, start, E);
        scan_kernel<<<1, 1024, 0, stream>>>(start, N + 1);
        hipMemcpyAsync(cursor, start, (size_t)N * sizeof(int),
                       hipMemcpyDeviceToDevice, stream);
        fill_kernel<<<1024, 256, 0, stream>>>(eidx, cursor, scol, E);
        gather_kernel<<<(N + 3) / 4, 256, 0, stream>>>(start, scol, y, z, N);
    } else {
        // ws only fits y: fall back to atomic scatter
        hipMemsetAsync(d_out, 0, (size_t)out_size * sizeof(float), stream);
        scatter_kernel<<<4096, 256, 0, stream>>>(eidx, y, z, E);
    }
}

// Round 5
// 149.000 us; speedup vs baseline: 1.6577x; 1.6577x over previous
//
#include <hip/hip_runtime.h>

// z = segment_sum( (x @ W_fc^T)[col], row )  -- alpha==1 (softmax over singleton dim)
// Linearity: z[n] = ( sum_{e: row[e]=n} x[col[e]] ) @ W_fc^T  -> apply W once per node.
//
// Pipeline: memset(start) -> hist(+rank) -> scan_local -> scan_add -> fill -> gather_fused

// ---------- hist: deg counts at cnt[r+1]; rank[e] = within-bucket order ----------
__global__ void hist_rank(const int* __restrict__ eidx, int* __restrict__ cnt,
                          int* __restrict__ rank, int E) {
    int i = blockIdx.x * blockDim.x + threadIdx.x;
    int n = gridDim.x * blockDim.x;
    for (int e = i; e < E; e += n) rank[e] = atomicAdd(&cnt[eidx[e] + 1], 1);
}

// ---------- scan phase 1: per-1024-tile inclusive scan + tile sums ----------
__global__ void scan_local(int* __restrict__ a, int* __restrict__ partial, int n) {
    __shared__ int sh[1024];
    int i = blockIdx.x * 1024 + threadIdx.x;
    sh[threadIdx.x] = (i < n) ? a[i] : 0;
    __syncthreads();
    for (int off = 1; off < 1024; off <<= 1) {
        int u = (threadIdx.x >= off) ? sh[threadIdx.x - off] : 0;
        __syncthreads();
        sh[threadIdx.x] += u;
        __syncthreads();
    }
    if (i < n) a[i] = sh[threadIdx.x];
    if (threadIdx.x == 1023) partial[blockIdx.x] = sh[1023];
}

// ---------- scan phase 2: each block adds prefix of tile sums (G<=64ish, wave-reduced) ----------
__global__ void scan_add(int* __restrict__ a, const int* __restrict__ partial, int n) {
    __shared__ int offsh;
    int b = blockIdx.x;
    if (threadIdx.x < 64) {
        int sum = 0;
        for (int t = threadIdx.x; t < b; t += 64) sum += partial[t];
        for (int d = 32; d > 0; d >>= 1) sum += __shfl_down(sum, d, 64);
        if (threadIdx.x == 0) offsh = sum;
    }
    __syncthreads();
    int i = b * 1024 + threadIdx.x;
    if (i < n) a[i] += offsh;
}

// ---------- fill: atomic-free CSR column scatter ----------
__global__ void fill_kernel(const int* __restrict__ eidx, const int* __restrict__ rank,
                            const int* __restrict__ start, int* __restrict__ scol, int E) {
    int i = blockIdx.x * blockDim.x + threadIdx.x;
    int n = gridDim.x * blockDim.x;
    for (int e = i; e < E; e += n) {
        int r = eidx[e];
        scol[start[r] + rank[e]] = eidx[E + e];
    }
}

// ---------- gather + fused linear: one wave per node; lane = input channel during
// accumulation, = output channel during the W epilogue (shfl-broadcast of s). ----------
__global__ void gather_fused(const int* __restrict__ start, const int* __restrict__ scol,
                             const float* __restrict__ x, const float* __restrict__ Wfc,
                             float* __restrict__ z, int N) {
    __shared__ float sWT[64][66];              // sWT[k][co] = Wfc[co][k]; pad -> 2-way max (free)
    for (int i = threadIdx.x; i < 4096; i += 256)
        sWT[i & 63][i >> 6] = Wfc[i];          // Wfc row-major [co][k]
    __syncthreads();
    int lane = threadIdx.x & 63;
    int node = blockIdx.x * 4 + (threadIdx.x >> 6);
    if (node >= N) return;
    int e0 = start[node], e1 = start[node + 1];
    float acc0 = 0.f, acc1 = 0.f;
    int j = e0;
    for (; j + 1 < e1; j += 2) {               // 2-deep ILP on dependent idx->row chain
        int c0 = scol[j], c1 = scol[j + 1];    // wave-uniform broadcast loads
        acc0 += x[(size_t)c0 * 64 + lane];     // coalesced 256 B/wave
        acc1 += x[(size_t)c1 * 64 + lane];
    }
    if (j < e1) acc0 += x[(size_t)scol[j] * 64 + lane];
    float s = acc0 + acc1;                     // lane k holds summed input channel k
    float zc = 0.f;
#pragma unroll
    for (int k = 0; k < 64; ++k) {
        float sk = __shfl(s, k, 64);           // broadcast s_k to all lanes
        zc = fmaf(sWT[k][lane], sk, zc);       // lane co accumulates W[co][k]*s_k
    }
    z[(size_t)node * 64 + lane] = zc;          // single non-atomic coalesced write
}

// ---------- fallback (ws too small for CSR): fc + atomic scatter ----------
__global__ void fc_kernel(const float* __restrict__ x, const float* __restrict__ Wfc,
                          float* __restrict__ y, int N) {
    __shared__ float sW[64][65];
    __shared__ float sX[4][64];
    for (int i = threadIdx.x; i < 64 * 64; i += 256) sW[i >> 6][i & 63] = Wfc[i];
    int r = threadIdx.x >> 6, co = threadIdx.x & 63;
    int gRow = (blockIdx.x << 2) + r;
    sX[r][co] = (gRow < N) ? x[gRow * 64 + co] : 0.f;
    __syncthreads();
    if (gRow >= N) return;
    float acc = 0.f;
#pragma unroll
    for (int k = 0; k < 64; ++k) acc = fmaf(sX[r][k], sW[co][k], acc);
    y[gRow * 64 + co] = acc;
}
__global__ void scatter_kernel(const int* __restrict__ eidx, const float* __restrict__ y,
                               float* __restrict__ z, int E) {
    int lane = threadIdx.x & 63;
    int g  = (int)((blockIdx.x * blockDim.x + threadIdx.x) >> 6);
    int nG = (int)((gridDim.x * blockDim.x) >> 6);
    for (int e = g; e < E; e += nG) {
        int r = eidx[e], c = eidx[E + e];
        atomicAdd(&z[r * 64 + lane], y[c * 64 + lane]);
    }
}

extern "C" void kernel_launch(void* const* d_in, const int* in_sizes, int n_in,
                              void* d_out, int out_size, void* d_ws, size_t ws_size,
                              hipStream_t stream) {
    const float* x    = (const float*)d_in[0];
    const int*   eidx = (const int*)d_in[1];
    const float* Wfc  = (const float*)d_in[3];   // d_in[2,4,5] unused (alpha==1)
    float*       z    = (float*)d_out;

    int N = in_sizes[0] / 64;
    int E = in_sizes[1] / 2;
    int G = (N + 1 + 1023) / 1024;               // scan tiles

    // workspace layout
    char* w = (char*)d_ws;
    size_t off = 0;
    int* start   = (int*)(w + off); off += (size_t)(N + 1) * sizeof(int);
    off = (off + 255) & ~(size_t)255;
    int* rank    = (int*)(w + off); off += (size_t)E * sizeof(int);
    off = (off + 255) & ~(size_t)255;
    int* scol    = (int*)(w + off); off += (size_t)E * sizeof(int);
    off = (off + 255) & ~(size_t)255;
    int* partial = (int*)(w + off); off += (size_t)G * sizeof(int);

    if (ws_size >= off) {
        hipMemsetAsync(start, 0, (size_t)(N + 1) * sizeof(int), stream);
        hist_rank<<<2048, 256, 0, stream>>>(eidx, start, rank, E);
        scan_local<<<G, 1024, 0, stream>>>(start, partial, N + 1);
        scan_add<<<G, 1024, 0, stream>>>(start, partial, N + 1);
        fill_kernel<<<2048, 256, 0, stream>>>(eidx, rank, start, scol, E);
        gather_fused<<<(N + 3) / 4, 256, 0, stream>>>(start, scol, x, Wfc, z, N);
    } else {
        // fallback: y in ws + atomic scatter
        float* y = (float*)d_ws;
        hipMemsetAsync(d_out, 0, (size_t)out_size * sizeof(float), stream);
        fc_kernel<<<(N + 3) / 4, 256, 0, stream>>>(x, Wfc, y, N);
        scatter_kernel<<<4096, 256, 0, stream>>>(eidx, y, z, E);
    }
}

// Round 6
// 132.662 us; speedup vs baseline: 1.8619x; 1.1232x over previous
//
#include <hip/hip_runtime.h>
#include <hip/hip_bf16.h>

// z = segment_sum( (x @ W_fc^T)[col], row )  -- alpha==1 (softmax over singleton dim)
// Linearity: z[n] = ( sum_{e: row[e]=n} x[col[e]] ) @ W_fc^T  -> apply W once per node.
// Pipeline: memset -> hist(+rank) -> scan_local -> scan_add -> fill -> cvt(bf16) -> gather_fused

// ---------- hist: deg counts at cnt[r+1]; rank[e] = within-bucket order ----------
__global__ void hist_rank(const int* __restrict__ eidx, int* __restrict__ cnt,
                          int* __restrict__ rank, int E) {
    int i = blockIdx.x * blockDim.x + threadIdx.x;
    int n = gridDim.x * blockDim.x;
    for (int e = i; e < E; e += n) rank[e] = atomicAdd(&cnt[eidx[e] + 1], 1);
}

// ---------- scan phase 1: per-1024-tile inclusive scan + tile sums ----------
__global__ void scan_local(int* __restrict__ a, int* __restrict__ partial, int n) {
    __shared__ int sh[1024];
    int i = blockIdx.x * 1024 + threadIdx.x;
    sh[threadIdx.x] = (i < n) ? a[i] : 0;
    __syncthreads();
    for (int off = 1; off < 1024; off <<= 1) {
        int u = (threadIdx.x >= off) ? sh[threadIdx.x - off] : 0;
        __syncthreads();
        sh[threadIdx.x] += u;
        __syncthreads();
    }
    if (i < n) a[i] = sh[threadIdx.x];
    if (threadIdx.x == 1023) partial[blockIdx.x] = sh[1023];
}

// ---------- scan phase 2: add prefix of tile sums ----------
__global__ void scan_add(int* __restrict__ a, const int* __restrict__ partial, int n) {
    __shared__ int offsh;
    int b = blockIdx.x;
    if (threadIdx.x < 64) {
        int sum = 0;
        for (int t = threadIdx.x; t < b; t += 64) sum += partial[t];
        for (int d = 32; d > 0; d >>= 1) sum += __shfl_down(sum, d, 64);
        if (threadIdx.x == 0) offsh = sum;
    }
    __syncthreads();
    int i = b * 1024 + threadIdx.x;
    if (i < n) a[i] += offsh;
}

// ---------- fill: atomic-free CSR column scatter ----------
__global__ void fill_kernel(const int* __restrict__ eidx, const int* __restrict__ rank,
                            const int* __restrict__ start, int* __restrict__ scol, int E) {
    int i = blockIdx.x * blockDim.x + threadIdx.x;
    int n = gridDim.x * blockDim.x;
    for (int e = i; e < E; e += n) {
        int r = eidx[e];
        scol[start[r] + rank[e]] = eidx[E + e];
    }
}

// ---------- cvt: x f32 -> bf16 (RNE), vectorized ----------
__device__ inline unsigned short f2bf(float f) {
    __hip_bfloat16 h = __float2bfloat16(f);
    return *reinterpret_cast<unsigned short*>(&h);
}
__global__ void cvt_kernel(const float4* __restrict__ x4, ushort4* __restrict__ xb4, int n4) {
    int i = blockIdx.x * blockDim.x + threadIdx.x;
    int n = gridDim.x * blockDim.x;
    for (; i < n4; i += n) {
        float4 v = x4[i];
        ushort4 o;
        o.x = f2bf(v.x); o.y = f2bf(v.y); o.z = f2bf(v.z); o.w = f2bf(v.w);
        xb4[i] = o;
    }
}

// ---------- gather + fused linear: one wave per node, 8-deep load pipeline ----------
__device__ inline float ldx(const unsigned short* xb, int c, int lane) {
    unsigned short u = xb[(size_t)c * 64 + lane];
    return __bfloat162float(*reinterpret_cast<__hip_bfloat16*>(&u));
}
__global__ __launch_bounds__(512) void gather_fused(
        const int* __restrict__ start, const int* __restrict__ scol,
        const unsigned short* __restrict__ xb, const float* __restrict__ Wfc,
        float* __restrict__ z, int N) {
    __shared__ float sW[64][68];   // row-major; stride 272B: 16B-aligned, bank-balanced for b128
    for (int i = threadIdx.x; i < 4096; i += 512)
        sW[i >> 6][i & 63] = Wfc[i];           // consecutive writes -> conflict-free
    __syncthreads();
    int lane = threadIdx.x & 63;
    int node = blockIdx.x * 8 + (threadIdx.x >> 6);
    if (node >= N) return;
    int e0 = start[node], e1 = start[node + 1];

    float a0=0,a1=0,a2=0,a3=0,a4=0,a5=0,a6=0,a7=0;
    int j = e0;
    if (e1 - j >= 8) {
        int c0=scol[j],c1=scol[j+1],c2=scol[j+2],c3=scol[j+3],
            c4=scol[j+4],c5=scol[j+5],c6=scol[j+6],c7=scol[j+7];
        j += 8;
        while (e1 - j >= 8) {
            int n0=scol[j],n1=scol[j+1],n2=scol[j+2],n3=scol[j+3],
                n4=scol[j+4],n5=scol[j+5],n6=scol[j+6],n7=scol[j+7];
            j += 8;
            a0 += ldx(xb,c0,lane); a1 += ldx(xb,c1,lane);
            a2 += ldx(xb,c2,lane); a3 += ldx(xb,c3,lane);
            a4 += ldx(xb,c4,lane); a5 += ldx(xb,c5,lane);
            a6 += ldx(xb,c6,lane); a7 += ldx(xb,c7,lane);
            c0=n0;c1=n1;c2=n2;c3=n3;c4=n4;c5=n5;c6=n6;c7=n7;
        }
        a0 += ldx(xb,c0,lane); a1 += ldx(xb,c1,lane);
        a2 += ldx(xb,c2,lane); a3 += ldx(xb,c3,lane);
        a4 += ldx(xb,c4,lane); a5 += ldx(xb,c5,lane);
        a6 += ldx(xb,c6,lane); a7 += ldx(xb,c7,lane);
    }
    for (; j < e1; ++j) a0 += ldx(xb, scol[j], lane);
    float s = ((a0+a4)+(a1+a5)) + ((a2+a6)+(a3+a7));   // lane k holds summed channel k

    // epilogue: z[node][lane] = sum_k W[lane][k] * s_k
    const float4* wrow = reinterpret_cast<const float4*>(&sW[lane][0]);
    float z0=0,z1=0,z2=0,z3=0;
#pragma unroll
    for (int m = 0; m < 16; ++m) {
        float4 w = wrow[m];
        z0 = fmaf(w.x, __shfl(s, 4*m+0, 64), z0);   // compile-time lane -> v_readlane
        z1 = fmaf(w.y, __shfl(s, 4*m+1, 64), z1);
        z2 = fmaf(w.z, __shfl(s, 4*m+2, 64), z2);
        z3 = fmaf(w.w, __shfl(s, 4*m+3, 64), z3);
    }
    z[(size_t)node * 64 + lane] = (z0+z1)+(z2+z3);
}

// ---------- fallback (ws too small for CSR): fc + atomic scatter ----------
__global__ void fc_kernel(const float* __restrict__ x, const float* __restrict__ Wfc,
                          float* __restrict__ y, int N) {
    __shared__ float sW[64][65];
    __shared__ float sX[4][64];
    for (int i = threadIdx.x; i < 64 * 64; i += 256) sW[i >> 6][i & 63] = Wfc[i];
    int r = threadIdx.x >> 6, co = threadIdx.x & 63;
    int gRow = (blockIdx.x << 2) + r;
    sX[r][co] = (gRow < N) ? x[gRow * 64 + co] : 0.f;
    __syncthreads();
    if (gRow >= N) return;
    float acc = 0.f;
#pragma unroll
    for (int k = 0; k < 64; ++k) acc = fmaf(sX[r][k], sW[co][k], acc);
    y[gRow * 64 + co] = acc;
}
__global__ void scatter_kernel(const int* __restrict__ eidx, const float* __restrict__ y,
                               float* __restrict__ z, int E) {
    int lane = threadIdx.x & 63;
    int g  = (int)((blockIdx.x * blockDim.x + threadIdx.x) >> 6);
    int nG = (int)((gridDim.x * blockDim.x) >> 6);
    for (int e = g; e < E; e += nG) {
        int r = eidx[e], c = eidx[E + e];
        atomicAdd(&z[r * 64 + lane], y[c * 64 + lane]);
    }
}

extern "C" void kernel_launch(void* const* d_in, const int* in_sizes, int n_in,
                              void* d_out, int out_size, void* d_ws, size_t ws_size,
                              hipStream_t stream) {
    const float* x    = (const float*)d_in[0];
    const int*   eidx = (const int*)d_in[1];
    const float* Wfc  = (const float*)d_in[3];   // d_in[2,4,5] unused (alpha==1)
    float*       z    = (float*)d_out;

    int N = in_sizes[0] / 64;
    int E = in_sizes[1] / 2;
    int G = (N + 1 + 1023) / 1024;               // scan tiles

    // workspace layout
    char* w = (char*)d_ws;
    size_t off = 0;
    int* start   = (int*)(w + off); off += (size_t)(N + 1) * sizeof(int);
    off = (off + 255) & ~(size_t)255;
    int* rank    = (int*)(w + off); off += (size_t)E * sizeof(int);
    off = (off + 255) & ~(size_t)255;
    int* scol    = (int*)(w + off); off += (size_t)E * sizeof(int);
    off = (off + 255) & ~(size_t)255;
    int* partial = (int*)(w + off); off += (size_t)G * sizeof(int);
    off = (off + 255) & ~(size_t)255;
    unsigned short* xb = (unsigned short*)(w + off); off += (size_t)N * 64 * sizeof(unsigned short);

    if (ws_size >= off) {
        hipMemsetAsync(start, 0, (size_t)(N + 1) * sizeof(int), stream);
        hist_rank<<<4096, 256, 0, stream>>>(eidx, start, rank, E);
        scan_local<<<G, 1024, 0, stream>>>(start, partial, N + 1);
        scan_add<<<G, 1024, 0, stream>>>(start, partial, N + 1);
        fill_kernel<<<4096, 256, 0, stream>>>(eidx, rank, start, scol, E);
        cvt_kernel<<<2048, 256, 0, stream>>>((const float4*)x, (ushort4*)xb, N * 16);
        gather_fused<<<(N + 7) / 8, 512, 0, stream>>>(start, scol, xb, Wfc, z, N);
    } else {
        // fallback: y in ws + atomic scatter
        float* y = (float*)d_ws;
        hipMemsetAsync(d_out, 0, (size_t)out_size * sizeof(float), stream);
        fc_kernel<<<(N + 3) / 4, 256, 0, stream>>>(x, Wfc, y, N);
        scatter_kernel<<<4096, 256, 0, stream>>>(eidx, y, z, E);
    }
}

// Round 7
// 110.423 us; speedup vs baseline: 2.2369x; 1.2014x over previous
//
#include <hip/hip_runtime.h>
#include <hip/hip_bf16.h>

// z = segment_sum( (x @ W_fc^T)[col], row )  -- alpha==1 (softmax over singleton dim)
// Round 7: un-fuse. y = x@W^T once per row (bf16), then pure gather with
// 4-edges-per-load (uint2/lane), no LDS, no per-node epilogue.
// Pipeline: memset -> hist(+rank) -> scan_local -> scan_add -> fill -> fc_bf16 -> gather4

__device__ inline unsigned short f2bf(float f) {
    __hip_bfloat16 h = __float2bfloat16(f);
    return *reinterpret_cast<unsigned short*>(&h);
}

// ---------- hist: deg counts at cnt[r+1]; rank[e] = within-bucket order ----------
__global__ void hist_rank(const int* __restrict__ eidx, int* __restrict__ cnt,
                          int* __restrict__ rank, int E) {
    int i = blockIdx.x * blockDim.x + threadIdx.x;
    int n = gridDim.x * blockDim.x;
    for (int e = i; e < E; e += n) rank[e] = atomicAdd(&cnt[eidx[e] + 1], 1);
}

// ---------- scan phase 1: per-1024-tile inclusive scan + tile sums ----------
__global__ void scan_local(int* __restrict__ a, int* __restrict__ partial, int n) {
    __shared__ int sh[1024];
    int i = blockIdx.x * 1024 + threadIdx.x;
    sh[threadIdx.x] = (i < n) ? a[i] : 0;
    __syncthreads();
    for (int off = 1; off < 1024; off <<= 1) {
        int u = (threadIdx.x >= off) ? sh[threadIdx.x - off] : 0;
        __syncthreads();
        sh[threadIdx.x] += u;
        __syncthreads();
    }
    if (i < n) a[i] = sh[threadIdx.x];
    if (threadIdx.x == 1023) partial[blockIdx.x] = sh[1023];
}

// ---------- scan phase 2: add prefix of tile sums ----------
__global__ void scan_add(int* __restrict__ a, const int* __restrict__ partial, int n) {
    __shared__ int offsh;
    int b = blockIdx.x;
    if (threadIdx.x < 64) {
        int sum = 0;
        for (int t = threadIdx.x; t < b; t += 64) sum += partial[t];
        for (int d = 32; d > 0; d >>= 1) sum += __shfl_down(sum, d, 64);
        if (threadIdx.x == 0) offsh = sum;
    }
    __syncthreads();
    int i = b * 1024 + threadIdx.x;
    if (i < n) a[i] += offsh;
}

// ---------- fill: atomic-free CSR column scatter ----------
__global__ void fill_kernel(const int* __restrict__ eidx, const int* __restrict__ rank,
                            const int* __restrict__ start, int* __restrict__ scol, int E) {
    int i = blockIdx.x * blockDim.x + threadIdx.x;
    int n = gridDim.x * blockDim.x;
    for (int e = i; e < E; e += n) {
        int r = eidx[e];
        scol[start[r] + rank[e]] = eidx[E + e];
    }
}

// ---------- fc: y[n][co] = sum_k x[n][k]*W[co][k], bf16 out; 16 rows/block ----------
__global__ __launch_bounds__(256) void fc_bf16(const float* __restrict__ x,
        const float* __restrict__ Wfc, unsigned short* __restrict__ y, int N) {
    __shared__ float sW[64][65];   // lane=co reads sW[co][k]: 2-way max (free)
    __shared__ float sX[16][64];   // reads are wave-uniform broadcasts
    for (int i = threadIdx.x; i < 4096; i += 256) sW[i >> 6][i & 63] = Wfc[i];
    int row0 = blockIdx.x << 4;
    for (int i = threadIdx.x; i < 1024; i += 256) {
        int r = i >> 6, k = i & 63, gr = row0 + r;
        sX[r][k] = (gr < N) ? x[(size_t)gr * 64 + k] : 0.f;
    }
    __syncthreads();
    int co = threadIdx.x & 63;
    int rq = threadIdx.x >> 6;           // wave-uniform: 4 rows per thread
    float a0 = 0, a1 = 0, a2 = 0, a3 = 0;
#pragma unroll
    for (int k = 0; k < 64; ++k) {
        float w = sW[co][k];
        a0 = fmaf(w, sX[4 * rq + 0][k], a0);
        a1 = fmaf(w, sX[4 * rq + 1][k], a1);
        a2 = fmaf(w, sX[4 * rq + 2][k], a2);
        a3 = fmaf(w, sX[4 * rq + 3][k], a3);
    }
    int g = row0 + 4 * rq;
    if (g + 3 < N) {
        y[(size_t)(g + 0) * 64 + co] = f2bf(a0);
        y[(size_t)(g + 1) * 64 + co] = f2bf(a1);
        y[(size_t)(g + 2) * 64 + co] = f2bf(a2);
        y[(size_t)(g + 3) * 64 + co] = f2bf(a3);
    } else {
        if (g + 0 < N) y[(size_t)(g + 0) * 64 + co] = f2bf(a0);
        if (g + 1 < N) y[(size_t)(g + 1) * 64 + co] = f2bf(a1);
        if (g + 2 < N) y[(size_t)(g + 2) * 64 + co] = f2bf(a2);
    }
}

// ---------- gather4: one wave/node; 16-lane groups read 4 edges per load ----------
__device__ inline void acc_bf8(const uint2* yb, int c, int ch4,
                               float& r0, float& r1, float& r2, float& r3) {
    uint2 u = yb[(size_t)c * 16 + ch4];             // 8 B/lane, 128 B per 16-lane group
    r0 += __uint_as_float(u.x << 16);
    r1 += __uint_as_float(u.x & 0xffff0000u);
    r2 += __uint_as_float(u.y << 16);
    r3 += __uint_as_float(u.y & 0xffff0000u);
}
__global__ __launch_bounds__(256) void gather4(const int* __restrict__ start,
        const int* __restrict__ scol, const uint2* __restrict__ yb,
        float4* __restrict__ z4, int N) {
    int lane = threadIdx.x & 63;
    int node = (blockIdx.x << 2) + (threadIdx.x >> 6);
    if (node >= N) return;
    int e0 = start[node], e1 = start[node + 1];
    int sub = lane >> 4;        // edge slot within group-of-4
    int ch4 = lane & 15;        // 4-channel group
    float A0=0,A1=0,A2=0,A3=0, B0=0,B1=0,B2=0,B3=0,
          C0=0,C1=0,C2=0,C3=0, D0=0,D1=0,D2=0,D3=0;
    for (int j = e0; j < e1; j += 16) {             // 16 edges in flight per iter
        int j0 = j + sub, j1 = j + 4 + sub, j2 = j + 8 + sub, j3 = j + 12 + sub;
        int c0 = (j0 < e1) ? scol[j0] : -1;         // broadcast within 16-lane group
        int c1 = (j1 < e1) ? scol[j1] : -1;
        int c2 = (j2 < e1) ? scol[j2] : -1;
        int c3 = (j3 < e1) ? scol[j3] : -1;
        if (c0 >= 0) acc_bf8(yb, c0, ch4, A0, A1, A2, A3);
        if (c1 >= 0) acc_bf8(yb, c1, ch4, B0, B1, B2, B3);
        if (c2 >= 0) acc_bf8(yb, c2, ch4, C0, C1, C2, C3);
        if (c3 >= 0) acc_bf8(yb, c3, ch4, D0, D1, D2, D3);
    }
    float r0 = (A0 + B0) + (C0 + D0);
    float r1 = (A1 + B1) + (C1 + D1);
    float r2 = (A2 + B2) + (C2 + D2);
    float r3 = (A3 + B3) + (C3 + D3);
    r0 += __shfl_xor(r0, 16, 64); r0 += __shfl_xor(r0, 32, 64);  // sum 4 sub-groups
    r1 += __shfl_xor(r1, 16, 64); r1 += __shfl_xor(r1, 32, 64);
    r2 += __shfl_xor(r2, 16, 64); r2 += __shfl_xor(r2, 32, 64);
    r3 += __shfl_xor(r3, 16, 64); r3 += __shfl_xor(r3, 32, 64);
    if (lane < 16)                                   // 16 lanes x float4 = 256 B row
        z4[(size_t)node * 16 + ch4] = make_float4(r0, r1, r2, r3);
}

// ---------- fallback (ws too small for CSR): fc f32 + atomic scatter ----------
__global__ void fc_kernel(const float* __restrict__ x, const float* __restrict__ Wfc,
                          float* __restrict__ y, int N) {
    __shared__ float sW[64][65];
    __shared__ float sX[4][64];
    for (int i = threadIdx.x; i < 64 * 64; i += 256) sW[i >> 6][i & 63] = Wfc[i];
    int r = threadIdx.x >> 6, co = threadIdx.x & 63;
    int gRow = (blockIdx.x << 2) + r;
    sX[r][co] = (gRow < N) ? x[gRow * 64 + co] : 0.f;
    __syncthreads();
    if (gRow >= N) return;
    float acc = 0.f;
#pragma unroll
    for (int k = 0; k < 64; ++k) acc = fmaf(sX[r][k], sW[co][k], acc);
    y[gRow * 64 + co] = acc;
}
__global__ void scatter_kernel(const int* __restrict__ eidx, const float* __restrict__ y,
                               float* __restrict__ z, int E) {
    int lane = threadIdx.x & 63;
    int g  = (int)((blockIdx.x * blockDim.x + threadIdx.x) >> 6);
    int nG = (int)((gridDim.x * blockDim.x) >> 6);
    for (int e = g; e < E; e += nG) {
        int r = eidx[e], c = eidx[E + e];
        atomicAdd(&z[r * 64 + lane], y[c * 64 + lane]);
    }
}

extern "C" void kernel_launch(void* const* d_in, const int* in_sizes, int n_in,
                              void* d_out, int out_size, void* d_ws, size_t ws_size,
                              hipStream_t stream) {
    const float* x    = (const float*)d_in[0];
    const int*   eidx = (const int*)d_in[1];
    const float* Wfc  = (const float*)d_in[3];   // d_in[2,4,5] unused (alpha==1)
    float*       z    = (float*)d_out;

    int N = in_sizes[0] / 64;
    int E = in_sizes[1] / 2;
    int G = (N + 1 + 1023) / 1024;               // scan tiles

    // workspace layout
    char* w = (char*)d_ws;
    size_t off = 0;
    int* start   = (int*)(w + off); off += (size_t)(N + 1) * sizeof(int);
    off = (off + 255) & ~(size_t)255;
    int* rank    = (int*)(w + off); off += (size_t)E * sizeof(int);
    off = (off + 255) & ~(size_t)255;
    int* scol    = (int*)(w + off); off += (size_t)E * sizeof(int);
    off = (off + 255) & ~(size_t)255;
    int* partial = (int*)(w + off); off += (size_t)G * sizeof(int);
    off = (off + 255) & ~(size_t)255;
    unsigned short* yb = (unsigned short*)(w + off); off += (size_t)N * 64 * sizeof(unsigned short);

    if (ws_size >= off) {
        hipMemsetAsync(start, 0, (size_t)(N + 1) * sizeof(int), stream);
        hist_rank<<<4096, 256, 0, stream>>>(eidx, start, rank, E);
        scan_local<<<G, 1024, 0, stream>>>(start, partial, N + 1);
        scan_add<<<G, 1024, 0, stream>>>(start, partial, N + 1);
        fill_kernel<<<4096, 256, 0, stream>>>(eidx, rank, start, scol, E);
        fc_bf16<<<(N + 15) / 16, 256, 0, stream>>>(x, Wfc, yb, N);
        gather4<<<(N + 3) / 4, 256, 0, stream>>>(start, scol, (const uint2*)yb,
                                                 (float4*)z, N);
    } else {
        // fallback: y f32 in ws + atomic scatter
        float* y = (float*)d_ws;
        hipMemsetAsync(d_out, 0, (size_t)out_size * sizeof(float), stream);
        fc_kernel<<<(N + 3) / 4, 256, 0, stream>>>(x, Wfc, y, N);
        scatter_kernel<<<4096, 256, 0, stream>>>(eidx, y, z, E);
    }
}

// Round 8
// 108.241 us; speedup vs baseline: 2.2819x; 1.0202x over previous
//
#include <hip/hip_runtime.h>
#include <hip/hip_bf16.h>

// z = segment_sum( (x @ W_fc^T)[col], row )  -- alpha==1 (softmax over singleton dim)
// Round 8: replace hipMemsetAsync (rocclr fillBuffer = 43 us!) with a
// grid-stride zero kernel. Pipeline otherwise unchanged:
// zero -> hist(+rank) -> scan_local -> scan_add -> fill -> fc_bf16 -> gather4

__device__ inline unsigned short f2bf(float f) {
    __hip_bfloat16 h = __float2bfloat16(f);
    return *reinterpret_cast<unsigned short*>(&h);
}

// ---------- zero: n ints, grid-stride ----------
__global__ void zero_kernel(int* __restrict__ a, int n) {
    int i = blockIdx.x * blockDim.x + threadIdx.x;
    int s = gridDim.x * blockDim.x;
    for (; i < n; i += s) a[i] = 0;
}

// ---------- hist: deg counts at cnt[r+1]; rank[e] = within-bucket order ----------
__global__ void hist_rank(const int* __restrict__ eidx, int* __restrict__ cnt,
                          int* __restrict__ rank, int E) {
    int i = blockIdx.x * blockDim.x + threadIdx.x;
    int n = gridDim.x * blockDim.x;
    for (int e = i; e < E; e += n) rank[e] = atomicAdd(&cnt[eidx[e] + 1], 1);
}

// ---------- scan phase 1: per-1024-tile inclusive scan + tile sums ----------
__global__ void scan_local(int* __restrict__ a, int* __restrict__ partial, int n) {
    __shared__ int sh[1024];
    int i = blockIdx.x * 1024 + threadIdx.x;
    sh[threadIdx.x] = (i < n) ? a[i] : 0;
    __syncthreads();
    for (int off = 1; off < 1024; off <<= 1) {
        int u = (threadIdx.x >= off) ? sh[threadIdx.x - off] : 0;
        __syncthreads();
        sh[threadIdx.x] += u;
        __syncthreads();
    }
    if (i < n) a[i] = sh[threadIdx.x];
    if (threadIdx.x == 1023) partial[blockIdx.x] = sh[1023];
}

// ---------- scan phase 2: add prefix of tile sums ----------
__global__ void scan_add(int* __restrict__ a, const int* __restrict__ partial, int n) {
    __shared__ int offsh;
    int b = blockIdx.x;
    if (threadIdx.x < 64) {
        int sum = 0;
        for (int t = threadIdx.x; t < b; t += 64) sum += partial[t];
        for (int d = 32; d > 0; d >>= 1) sum += __shfl_down(sum, d, 64);
        if (threadIdx.x == 0) offsh = sum;
    }
    __syncthreads();
    int i = b * 1024 + threadIdx.x;
    if (i < n) a[i] += offsh;
}

// ---------- fill: atomic-free CSR column scatter ----------
__global__ void fill_kernel(const int* __restrict__ eidx, const int* __restrict__ rank,
                            const int* __restrict__ start, int* __restrict__ scol, int E) {
    int i = blockIdx.x * blockDim.x + threadIdx.x;
    int n = gridDim.x * blockDim.x;
    for (int e = i; e < E; e += n) {
        int r = eidx[e];
        scol[start[r] + rank[e]] = eidx[E + e];
    }
}

// ---------- fc: y[n][co] = sum_k x[n][k]*W[co][k], bf16 out; 16 rows/block ----------
__global__ __launch_bounds__(256) void fc_bf16(const float* __restrict__ x,
        const float* __restrict__ Wfc, unsigned short* __restrict__ y, int N) {
    __shared__ float sW[64][65];   // lane=co reads sW[co][k]: 2-way max (free)
    __shared__ float sX[16][64];   // reads are wave-uniform broadcasts
    for (int i = threadIdx.x; i < 4096; i += 256) sW[i >> 6][i & 63] = Wfc[i];
    int row0 = blockIdx.x << 4;
    for (int i = threadIdx.x; i < 1024; i += 256) {
        int r = i >> 6, k = i & 63, gr = row0 + r;
        sX[r][k] = (gr < N) ? x[(size_t)gr * 64 + k] : 0.f;
    }
    __syncthreads();
    int co = threadIdx.x & 63;
    int rq = threadIdx.x >> 6;           // wave-uniform: 4 rows per thread
    float a0 = 0, a1 = 0, a2 = 0, a3 = 0;
#pragma unroll
    for (int k = 0; k < 64; ++k) {
        float w = sW[co][k];
        a0 = fmaf(w, sX[4 * rq + 0][k], a0);
        a1 = fmaf(w, sX[4 * rq + 1][k], a1);
        a2 = fmaf(w, sX[4 * rq + 2][k], a2);
        a3 = fmaf(w, sX[4 * rq + 3][k], a3);
    }
    int g = row0 + 4 * rq;
    if (g + 3 < N) {
        y[(size_t)(g + 0) * 64 + co] = f2bf(a0);
        y[(size_t)(g + 1) * 64 + co] = f2bf(a1);
        y[(size_t)(g + 2) * 64 + co] = f2bf(a2);
        y[(size_t)(g + 3) * 64 + co] = f2bf(a3);
    } else {
        if (g + 0 < N) y[(size_t)(g + 0) * 64 + co] = f2bf(a0);
        if (g + 1 < N) y[(size_t)(g + 1) * 64 + co] = f2bf(a1);
        if (g + 2 < N) y[(size_t)(g + 2) * 64 + co] = f2bf(a2);
    }
}

// ---------- gather4: one wave/node; 16-lane groups read 4 edges per load ----------
__device__ inline void acc_bf8(const uint2* yb, int c, int ch4,
                               float& r0, float& r1, float& r2, float& r3) {
    uint2 u = yb[(size_t)c * 16 + ch4];             // 8 B/lane, 128 B per 16-lane group
    r0 += __uint_as_float(u.x << 16);
    r1 += __uint_as_float(u.x & 0xffff0000u);
    r2 += __uint_as_float(u.y << 16);
    r3 += __uint_as_float(u.y & 0xffff0000u);
}
__global__ __launch_bounds__(256) void gather4(const int* __restrict__ start,
        const int* __restrict__ scol, const uint2* __restrict__ yb,
        float4* __restrict__ z4, int N) {
    int lane = threadIdx.x & 63;
    int node = (blockIdx.x << 2) + (threadIdx.x >> 6);
    if (node >= N) return;
    int e0 = start[node], e1 = start[node + 1];
    int sub = lane >> 4;        // edge slot within group-of-4
    int ch4 = lane & 15;        // 4-channel group
    float A0=0,A1=0,A2=0,A3=0, B0=0,B1=0,B2=0,B3=0,
          C0=0,C1=0,C2=0,C3=0, D0=0,D1=0,D2=0,D3=0;
    for (int j = e0; j < e1; j += 16) {             // 16 edges in flight per iter
        int j0 = j + sub, j1 = j + 4 + sub, j2 = j + 8 + sub, j3 = j + 12 + sub;
        int c0 = (j0 < e1) ? scol[j0] : -1;         // broadcast within 16-lane group
        int c1 = (j1 < e1) ? scol[j1] : -1;
        int c2 = (j2 < e1) ? scol[j2] : -1;
        int c3 = (j3 < e1) ? scol[j3] : -1;
        if (c0 >= 0) acc_bf8(yb, c0, ch4, A0, A1, A2, A3);
        if (c1 >= 0) acc_bf8(yb, c1, ch4, B0, B1, B2, B3);
        if (c2 >= 0) acc_bf8(yb, c2, ch4, C0, C1, C2, C3);
        if (c3 >= 0) acc_bf8(yb, c3, ch4, D0, D1, D2, D3);
    }
    float r0 = (A0 + B0) + (C0 + D0);
    float r1 = (A1 + B1) + (C1 + D1);
    float r2 = (A2 + B2) + (C2 + D2);
    float r3 = (A3 + B3) + (C3 + D3);
    r0 += __shfl_xor(r0, 16, 64); r0 += __shfl_xor(r0, 32, 64);  // sum 4 sub-groups
    r1 += __shfl_xor(r1, 16, 64); r1 += __shfl_xor(r1, 32, 64);
    r2 += __shfl_xor(r2, 16, 64); r2 += __shfl_xor(r2, 32, 64);
    r3 += __shfl_xor(r3, 16, 64); r3 += __shfl_xor(r3, 32, 64);
    if (lane < 16)                                   // 16 lanes x float4 = 256 B row
        z4[(size_t)node * 16 + ch4] = make_float4(r0, r1, r2, r3);
}

// ---------- fallback (ws too small for CSR): fc f32 + atomic scatter ----------
__global__ void fc_kernel(const float* __restrict__ x, const float* __restrict__ Wfc,
                          float* __restrict__ y, int N) {
    __shared__ float sW[64][65];
    __shared__ float sX[4][64];
    for (int i = threadIdx.x; i < 64 * 64; i += 256) sW[i >> 6][i & 63] = Wfc[i];
    int r = threadIdx.x >> 6, co = threadIdx.x & 63;
    int gRow = (blockIdx.x << 2) + r;
    sX[r][co] = (gRow < N) ? x[gRow * 64 + co] : 0.f;
    __syncthreads();
    if (gRow >= N) return;
    float acc = 0.f;
#pragma unroll
    for (int k = 0; k < 64; ++k) acc = fmaf(sX[r][k], sW[co][k], acc);
    y[gRow * 64 + co] = acc;
}
__global__ void scatter_kernel(const int* __restrict__ eidx, const float* __restrict__ y,
                               float* __restrict__ z, int E) {
    int lane = threadIdx.x & 63;
    int g  = (int)((blockIdx.x * blockDim.x + threadIdx.x) >> 6);
    int nG = (int)((gridDim.x * blockDim.x) >> 6);
    for (int e = g; e < E; e += nG) {
        int r = eidx[e], c = eidx[E + e];
        atomicAdd(&z[r * 64 + lane], y[c * 64 + lane]);
    }
}

extern "C" void kernel_launch(void* const* d_in, const int* in_sizes, int n_in,
                              void* d_out, int out_size, void* d_ws, size_t ws_size,
                              hipStream_t stream) {
    const float* x    = (const float*)d_in[0];
    const int*   eidx = (const int*)d_in[1];
    const float* Wfc  = (const float*)d_in[3];   // d_in[2,4,5] unused (alpha==1)
    float*       z    = (float*)d_out;

    int N = in_sizes[0] / 64;
    int E = in_sizes[1] / 2;
    int G = (N + 1 + 1023) / 1024;               // scan tiles

    // workspace layout
    char* w = (char*)d_ws;
    size_t off = 0;
    int* start   = (int*)(w + off); off += (size_t)(N + 1) * sizeof(int);
    off = (off + 255) & ~(size_t)255;
    int* rank    = (int*)(w + off); off += (size_t)E * sizeof(int);
    off = (off + 255) & ~(size_t)255;
    int* scol    = (int*)(w + off); off += (size_t)E * sizeof(int);
    off = (off + 255) & ~(size_t)255;
    int* partial = (int*)(w + off); off += (size_t)G * sizeof(int);
    off = (off + 255) & ~(size_t)255;
    unsigned short* yb = (unsigned short*)(w + off); off += (size_t)N * 64 * sizeof(unsigned short);

    if (ws_size >= off) {
        zero_kernel<<<512, 256, 0, stream>>>(start, N + 1);
        hist_rank<<<4096, 256, 0, stream>>>(eidx, start, rank, E);
        scan_local<<<G, 1024, 0, stream>>>(start, partial, N + 1);
        scan_add<<<G, 1024, 0, stream>>>(start, partial, N + 1);
        fill_kernel<<<4096, 256, 0, stream>>>(eidx, rank, start, scol, E);
        fc_bf16<<<(N + 15) / 16, 256, 0, stream>>>(x, Wfc, yb, N);
        gather4<<<(N + 3) / 4, 256, 0, stream>>>(start, scol, (const uint2*)yb,
                                                 (float4*)z, N);
    } else {
        // fallback: y f32 in ws + atomic scatter
        float* y = (float*)d_ws;
        hipMemsetAsync(d_out, 0, (size_t)out_size * sizeof(float), stream);
        fc_kernel<<<(N + 3) / 4, 256, 0, stream>>>(x, Wfc, y, N);
        scatter_kernel<<<4096, 256, 0, stream>>>(eidx, y, z, E);
    }
}